// Round 1
// baseline (148.671 us; speedup 1.0000x reference)
//
#include <hip/hip_runtime.h>
#include <stdint.h>

// ============================ problem dims ============================
// hidden_states [4,2048,2048] f32, rows R=8192, H=2048, BD=N=VBD=256, top-8
// out = primary + sigmoid(top1) * gelu_lowrank(softmax_top8 @ gathered vals)
// Key restructure: down-proj is linear -> precompute PV = slot_values @ Wd^T
// (256x256) and gather from PV instead of materializing aux[8192][2048].

typedef float f32x4 __attribute__((ext_vector_type(4)));
typedef unsigned short u16x8 __attribute__((ext_vector_type(8)));
typedef unsigned short u16x4 __attribute__((ext_vector_type(4)));
typedef __bf16 bf16x8 __attribute__((ext_vector_type(8)));

// ============================ ws layout (bytes) ============================
#define WS_QW    0u          // u16 [256*2048]  q_proj_w bf16
#define WS_SK    1048576u    // u16 [256*256]   slot_keys bf16
#define WS_SV    1179648u    // u16 [256*2048]  slot_values bf16
#define WS_VDW   2228224u    // u16 [256*2048]  value_down_w bf16
#define WS_VUP   3276800u    // u16 [2048*256]  value_up_w bf16
#define WS_REL   4325376u    // f32 [256]       log(reliability)
#define WS_PV    4326400u    // f32 [256*256]   slot_values @ Wd^T
#define WS_GATE  4588544u    // f32 [8192]      sigmoid(top1)
#define WS_QP    4621312u    // f32 [2][8192][256] query split-K partials
#define WS_D     21398528u   // u16 [8192*256]  gelu(down) bf16
// total ~24.4 MB

static __device__ __forceinline__ unsigned short f2bf(float f) {
  union { float f; unsigned int u; } v; v.f = f;
  unsigned int r = v.u + 0x7FFFu + ((v.u >> 16) & 1u);
  return (unsigned short)(r >> 16);
}
static __device__ __forceinline__ bf16x8 as_bf16(u16x8 v) {
  return __builtin_bit_cast(bf16x8, v);
}
static __device__ __forceinline__ float gelu_tanh(float x) {
  float u = 0.7978845608028654f * (x + 0.044715f * x * x * x);
  return 0.5f * x * (1.0f + tanhf(u));
}

// ============================ K0: convert weights ============================
__global__ void k_prep(const float* __restrict__ qw, const float* __restrict__ sk,
                       const float* __restrict__ sv, const float* __restrict__ vdw,
                       const float* __restrict__ vup, const float* __restrict__ rel,
                       unsigned char* __restrict__ ws) {
  unsigned short* o_qw  = (unsigned short*)(ws + WS_QW);
  unsigned short* o_sk  = (unsigned short*)(ws + WS_SK);
  unsigned short* o_sv  = (unsigned short*)(ws + WS_SV);
  unsigned short* o_vdw = (unsigned short*)(ws + WS_VDW);
  unsigned short* o_vup = (unsigned short*)(ws + WS_VUP);
  float* o_rel = (float*)(ws + WS_REL);
  int tid = blockIdx.x * blockDim.x + threadIdx.x;
  int stride = gridDim.x * blockDim.x;
  for (int g = tid; g < 540736; g += stride) {
    const float* src; unsigned short* dst; int i;
    if      (g < 131072) { src = qw;  dst = o_qw;  i = g; }
    else if (g < 147456) { src = sk;  dst = o_sk;  i = g - 131072; }
    else if (g < 278528) { src = sv;  dst = o_sv;  i = g - 147456; }
    else if (g < 409600) { src = vdw; dst = o_vdw; i = g - 278528; }
    else if (g < 540672) { src = vup; dst = o_vup; i = g - 409600; }
    else {
      int i4 = (g - 540672) * 4;
      #pragma unroll
      for (int j = 0; j < 4; j++) o_rel[i4 + j] = logf(fmaxf(rel[i4 + j], 1e-10f));
      continue;
    }
    f32x4 v = *(const f32x4*)(src + (size_t)i * 4);
    u16x4 o;
    #pragma unroll
    for (int j = 0; j < 4; j++) o[j] = f2bf(v[j]);
    *(u16x4*)(dst + (size_t)i * 4) = o;
  }
}

// ============================ K_PV: PV = sv @ vdw^T ============================
// 64 blocks, each a 32x32 tile over K=2048. 4 waves, one 16x16 frag each.
__global__ __launch_bounds__(256, 2) void k_pv(unsigned char* __restrict__ ws) {
  const unsigned short* sv  = (const unsigned short*)(ws + WS_SV);
  const unsigned short* vdw = (const unsigned short*)(ws + WS_VDW);
  float* PV = (float*)(ws + WS_PV);
  __shared__ __align__(16) unsigned short As[32 * 64];
  __shared__ __align__(16) unsigned short Bs[32 * 64];
  int t = threadIdx.x, lane = t & 63, w = t >> 6;
  int nt = blockIdx.x >> 3, vt = blockIdx.x & 7;
  int mf = w >> 1, nf = w & 1;
  f32x4 acc = {0.f, 0.f, 0.f, 0.f};
  int r = t >> 3, c = t & 7;
  int sw8 = (c ^ (r & 7)) * 8;
  for (int k0 = 0; k0 < 2048; k0 += 64) {
    __syncthreads();
    *(u16x8*)&As[r * 64 + sw8] = *(const u16x8*)&sv[(size_t)(nt * 32 + r) * 2048 + k0 + c * 8];
    *(u16x8*)&Bs[r * 64 + sw8] = *(const u16x8*)&vdw[(size_t)(vt * 32 + r) * 2048 + k0 + c * 8];
    __syncthreads();
    #pragma unroll
    for (int kk = 0; kk < 2; kk++) {
      int ck = kk * 4 + (lane >> 4);
      int ar = mf * 16 + (lane & 15);
      int br = nf * 16 + (lane & 15);
      bf16x8 a = as_bf16(*(const u16x8*)&As[ar * 64 + ((ck ^ (ar & 7)) * 8)]);
      bf16x8 b = as_bf16(*(const u16x8*)&Bs[br * 64 + ((ck ^ (br & 7)) * 8)]);
      acc = __builtin_amdgcn_mfma_f32_16x16x32_bf16(a, b, acc, 0, 0, 0);
    }
  }
  int row = nt * 32 + mf * 16 + (lane >> 4) * 4;
  int col = vt * 32 + nf * 16 + (lane & 15);
  #pragma unroll
  for (int j = 0; j < 4; j++) PV[(row + j) * 256 + col] = acc[j];
}

// ============================ K1: query GEMM (split-K=2) ============================
// qpart[ks][r][d] = hs[r, ks*1024 : +1024] @ qw^T.  BM=64, BN=256(all of BD).
// 256 blocks (128 row tiles x 2 k-slices), 4 waves, wave = 64x64.
__global__ __launch_bounds__(256, 2) void k_query(const float* __restrict__ hs,
                                                  unsigned char* __restrict__ ws) {
  const unsigned short* qw = (const unsigned short*)(ws + WS_QW);
  float* qp = (float*)(ws + WS_QP);
  __shared__ __align__(16) unsigned short As[64 * 64];    // 8 KB
  __shared__ __align__(16) unsigned short Bs[256 * 64];   // 32 KB
  int t = threadIdx.x, lane = t & 63, w = t >> 6;
  int rt = blockIdx.x >> 1, ks = blockIdx.x & 1;
  int row0 = rt * 64, kbase = ks * 1024;
  f32x4 acc[4][4] = {};
  int ar = t >> 2, aq = t & 3;   // A staging: row ar, 16-col chunk aq
  for (int k0 = 0; k0 < 1024; k0 += 64) {
    int kk0 = kbase + k0;
    __syncthreads();
    { // A: 64x64 fp32 -> bf16, swizzled
      const float* src = hs + (size_t)(row0 + ar) * 2048 + kk0 + aq * 16;
      f32x4 v0 = *(const f32x4*)(src);
      f32x4 v1 = *(const f32x4*)(src + 4);
      f32x4 v2 = *(const f32x4*)(src + 8);
      f32x4 v3 = *(const f32x4*)(src + 12);
      u16x8 p0, p1;
      #pragma unroll
      for (int j = 0; j < 4; j++) {
        p0[j] = f2bf(v0[j]); p0[4 + j] = f2bf(v1[j]);
        p1[j] = f2bf(v2[j]); p1[4 + j] = f2bf(v3[j]);
      }
      int c0 = aq * 2;
      *(u16x8*)&As[ar * 64 + ((c0 ^ (ar & 7)) * 8)]       = p0;
      *(u16x8*)&As[ar * 64 + (((c0 + 1) ^ (ar & 7)) * 8)] = p1;
    }
    #pragma unroll
    for (int i = 0; i < 8; i++) { // B: 256x64 bf16, swizzled
      int id = i * 256 + t, n = id >> 3, c = id & 7;
      u16x8 v = *(const u16x8*)&qw[(size_t)n * 2048 + kk0 + c * 8];
      *(u16x8*)&Bs[n * 64 + ((c ^ (n & 7)) * 8)] = v;
    }
    __syncthreads();
    #pragma unroll
    for (int kk = 0; kk < 2; kk++) {
      int ck = kk * 4 + (lane >> 4);
      bf16x8 a[4], b[4];
      #pragma unroll
      for (int mf = 0; mf < 4; mf++) {
        int arow = mf * 16 + (lane & 15);
        a[mf] = as_bf16(*(const u16x8*)&As[arow * 64 + ((ck ^ (arow & 7)) * 8)]);
      }
      #pragma unroll
      for (int nf = 0; nf < 4; nf++) {
        int brow = w * 64 + nf * 16 + (lane & 15);
        b[nf] = as_bf16(*(const u16x8*)&Bs[brow * 64 + ((ck ^ (brow & 7)) * 8)]);
      }
      #pragma unroll
      for (int mf = 0; mf < 4; mf++)
        #pragma unroll
        for (int nf = 0; nf < 4; nf++)
          acc[mf][nf] = __builtin_amdgcn_mfma_f32_16x16x32_bf16(a[mf], b[nf], acc[mf][nf], 0, 0, 0);
    }
  }
  float* outp = qp + (size_t)ks * 8192 * 256;
  #pragma unroll
  for (int mf = 0; mf < 4; mf++) {
    int row = row0 + mf * 16 + (lane >> 4) * 4;
    #pragma unroll
    for (int nf = 0; nf < 4; nf++) {
      int col = w * 64 + nf * 16 + (lane & 15);
      #pragma unroll
      for (int j = 0; j < 4; j++) outp[(size_t)(row + j) * 256 + col] = acc[mf][nf][j];
    }
  }
}

// ============================ K2: scores + top8 + softmax + PV gather ============================
#define QSTR 264   // ushort stride (528B = 33*16 -> 2-way banks, 16B aligned)
#define SSTR 260
static __device__ __forceinline__ void top8_ins(float (&bs)[8], int (&bi)[8], float s, int idx) {
  if (s > bs[7]) {
    bs[7] = s; bi[7] = idx;
    #pragma unroll
    for (int j = 7; j > 0; j--) {
      if (bs[j] > bs[j - 1]) {
        float ts = bs[j]; bs[j] = bs[j - 1]; bs[j - 1] = ts;
        int ti = bi[j]; bi[j] = bi[j - 1]; bi[j - 1] = ti;
      }
    }
  }
}
__global__ __launch_bounds__(256, 2) void k_score(unsigned char* __restrict__ ws) {
  const float* qp = (const float*)(ws + WS_QP);
  const unsigned short* sk = (const unsigned short*)(ws + WS_SK);
  const float* relm = (const float*)(ws + WS_REL);
  const float* PV = (const float*)(ws + WS_PV);
  float* gates = (float*)(ws + WS_GATE);
  unsigned short* D = (unsigned short*)(ws + WS_D);
  __shared__ __align__(16) unsigned short Qs[32 * QSTR];
  __shared__ __align__(16) float Ss[32 * SSTR];
  __shared__ float cs[32][64];
  __shared__ unsigned char ci[32][64];
  __shared__ float w8[32][8];
  __shared__ int i8[32][8];
  int t = threadIdx.x, lane = t & 63, w = t >> 6;
  int row0 = blockIdx.x * 32;
  // phase 1: query = qpart0 + qpart1 -> bf16 -> LDS
  #pragma unroll
  for (int i = 0; i < 8; i++) {
    int id = i * 256 + t, r = id >> 6, c4 = id & 63;
    const float* p0 = qp + (size_t)(row0 + r) * 256 + c4 * 4;
    f32x4 a = *(const f32x4*)p0;
    f32x4 b = *(const f32x4*)(p0 + 8192 * 256);
    u16x4 o;
    #pragma unroll
    for (int j = 0; j < 4; j++) o[j] = f2bf(a[j] + b[j]);
    *(u16x4*)&Qs[r * QSTR + c4 * 4] = o;
  }
  __syncthreads();
  // phase 2: scores[32][256] = Q @ sk^T / 16 + rel_mask
  {
    f32x4 acc[2][4] = {};
    for (int ksb = 0; ksb < 8; ksb++) {
      int ck = lane >> 4;
      bf16x8 a[2];
      #pragma unroll
      for (int mf = 0; mf < 2; mf++) {
        int arow = mf * 16 + (lane & 15);
        a[mf] = as_bf16(*(const u16x8*)&Qs[arow * QSTR + ksb * 32 + ck * 8]);
      }
      #pragma unroll
      for (int nf = 0; nf < 4; nf++) {
        int n = w * 64 + nf * 16 + (lane & 15);
        bf16x8 b = as_bf16(*(const u16x8*)&sk[(size_t)n * 256 + ksb * 32 + ck * 8]);
        #pragma unroll
        for (int mf = 0; mf < 2; mf++)
          acc[mf][nf] = __builtin_amdgcn_mfma_f32_16x16x32_bf16(a[mf], b, acc[mf][nf], 0, 0, 0);
      }
    }
    #pragma unroll
    for (int mf = 0; mf < 2; mf++)
      #pragma unroll
      for (int nf = 0; nf < 4; nf++) {
        int n = w * 64 + nf * 16 + (lane & 15);
        float rm = relm[n];
        int rr = mf * 16 + (lane >> 4) * 4;
        #pragma unroll
        for (int j = 0; j < 4; j++) Ss[(rr + j) * SSTR + n] = acc[mf][nf][j] * 0.0625f + rm;
      }
  }
  __syncthreads();
  // phase 3a: per-thread top8 over a 32-col chunk
  {
    int r = t >> 3, ch = t & 7;
    float bs[8]; int bi[8];
    #pragma unroll
    for (int j = 0; j < 8; j++) { bs[j] = -3.402823466e38f; bi[j] = 0; }
    for (int c = 0; c < 32; c++) top8_ins(bs, bi, Ss[r * SSTR + ch * 32 + c], ch * 32 + c);
    #pragma unroll
    for (int j = 0; j < 8; j++) { cs[r][ch * 8 + j] = bs[j]; ci[r][ch * 8 + j] = (unsigned char)bi[j]; }
  }
  __syncthreads();
  // phase 3b: merge 64 candidates, softmax, gate
  if ((t & 7) == 0) {
    int r = t >> 3;
    float bs[8]; int bi[8];
    #pragma unroll
    for (int j = 0; j < 8; j++) { bs[j] = -3.402823466e38f; bi[j] = 0; }
    for (int q = 0; q < 64; q++) top8_ins(bs, bi, cs[r][q], (int)ci[r][q]);
    float m = bs[0], sum = 0.f, e[8];
    #pragma unroll
    for (int j = 0; j < 8; j++) { e[j] = expf(bs[j] - m); sum += e[j]; }
    float inv = 1.f / sum;
    #pragma unroll
    for (int j = 0; j < 8; j++) { w8[r][j] = e[j] * inv; i8[r][j] = bi[j]; }
    gates[row0 + r] = 1.f / (1.f + expf(-m));
  }
  __syncthreads();
  // phase 4: D[r,v] = gelu( sum_k w_k * PV[idx_k, v] ) -> bf16
  {
    int r = t >> 3, ch = t & 7;
    float accv[32];
    #pragma unroll
    for (int j = 0; j < 32; j++) accv[j] = 0.f;
    #pragma unroll
    for (int k = 0; k < 8; k++) {
      float wk = w8[r][k];
      const float* pv = PV + (size_t)i8[r][k] * 256 + ch * 32;
      #pragma unroll
      for (int v4 = 0; v4 < 8; v4++) {
        f32x4 p = *(const f32x4*)(pv + v4 * 4);
        #pragma unroll
        for (int j = 0; j < 4; j++) accv[v4 * 4 + j] += wk * p[j];
      }
    }
    unsigned short* dd = D + (size_t)(row0 + r) * 256 + ch * 32;
    #pragma unroll
    for (int v8 = 0; v8 < 4; v8++) {
      u16x8 o;
      #pragma unroll
      for (int j = 0; j < 8; j++) o[j] = f2bf(gelu_tanh(accv[v8 * 8 + j]));
      *(u16x8*)&dd[v8 * 8] = o;
    }
  }
}

// ============================ K3: up-GEMM + epilogue ============================
// out[r,h] = primary[r,h] + gate[r] * (D[r,:] @ vup[h,:])   K=256
// 1024 blocks (64 row x 16 col tiles), XCD-chunk swizzle, 4 waves 2x2.
__global__ __launch_bounds__(256, 2) void k_out(const float* __restrict__ primary,
                                                float* __restrict__ out,
                                                unsigned char* __restrict__ ws) {
  const unsigned short* D = (const unsigned short*)(ws + WS_D);
  const unsigned short* vup = (const unsigned short*)(ws + WS_VUP);
  const float* gates = (const float*)(ws + WS_GATE);
  __shared__ __align__(16) unsigned short As[128 * 64];
  __shared__ __align__(16) unsigned short Bs[128 * 64];
  __shared__ float gate_s[128];
  int t = threadIdx.x, lane = t & 63, w = t >> 6;
  int bid = blockIdx.x;
  int L = (bid & 7) * 128 + (bid >> 3);   // bijective: 1024 % 8 == 0
  int rt = L >> 4, ct = L & 15;
  int wm = w >> 1, wn = w & 1;
  f32x4 acc[4][4] = {};
  if (t < 128) gate_s[t] = gates[rt * 128 + t];
  for (int k0 = 0; k0 < 256; k0 += 64) {
    __syncthreads();
    #pragma unroll
    for (int i = 0; i < 4; i++) {
      int id = i * 256 + t, r = id >> 3, c = id & 7;
      int sw8 = (c ^ (r & 7)) * 8;
      *(u16x8*)&As[r * 64 + sw8] = *(const u16x8*)&D[(size_t)(rt * 128 + r) * 256 + k0 + c * 8];
      *(u16x8*)&Bs[r * 64 + sw8] = *(const u16x8*)&vup[(size_t)(ct * 128 + r) * 256 + k0 + c * 8];
    }
    __syncthreads();
    #pragma unroll
    for (int kk = 0; kk < 2; kk++) {
      int ck = kk * 4 + (lane >> 4);
      bf16x8 a[4], b[4];
      #pragma unroll
      for (int mf = 0; mf < 4; mf++) {
        int ar = wm * 64 + mf * 16 + (lane & 15);
        a[mf] = as_bf16(*(const u16x8*)&As[ar * 64 + ((ck ^ (ar & 7)) * 8)]);
      }
      #pragma unroll
      for (int nf = 0; nf < 4; nf++) {
        int br = wn * 64 + nf * 16 + (lane & 15);
        b[nf] = as_bf16(*(const u16x8*)&Bs[br * 64 + ((ck ^ (br & 7)) * 8)]);
      }
      #pragma unroll
      for (int mf = 0; mf < 4; mf++)
        #pragma unroll
        for (int nf = 0; nf < 4; nf++)
          acc[mf][nf] = __builtin_amdgcn_mfma_f32_16x16x32_bf16(a[mf], b[nf], acc[mf][nf], 0, 0, 0);
    }
  }
  #pragma unroll
  for (int mf = 0; mf < 4; mf++) {
    int rloc = wm * 64 + mf * 16 + (lane >> 4) * 4;
    int row = rt * 128 + rloc;
    #pragma unroll
    for (int nf = 0; nf < 4; nf++) {
      int col = ct * 128 + wn * 64 + nf * 16 + (lane & 15);
      #pragma unroll
      for (int j = 0; j < 4; j++) {
        size_t o = (size_t)(row + j) * 2048 + col;
        out[o] = primary[o] + gate_s[rloc + j] * acc[mf][nf][j];
      }
    }
  }
}

// ============================ launch ============================
extern "C" void kernel_launch(void* const* d_in, const int* in_sizes, int n_in,
                              void* d_out, int out_size, void* d_ws, size_t ws_size,
                              hipStream_t stream) {
  const float* hs      = (const float*)d_in[0];
  const float* primary = (const float*)d_in[1];
  const float* qw      = (const float*)d_in[2];
  const float* sk      = (const float*)d_in[3];
  const float* sv      = (const float*)d_in[4];
  const float* rel     = (const float*)d_in[5];
  const float* vdw     = (const float*)d_in[6];
  const float* vup     = (const float*)d_in[7];
  unsigned char* ws = (unsigned char*)d_ws;
  float* out = (float*)d_out;

  k_prep<<<dim3(256), dim3(256), 0, stream>>>(qw, sk, sv, vdw, vup, rel, ws);
  k_pv<<<dim3(64), dim3(256), 0, stream>>>(ws);
  k_query<<<dim3(256), dim3(256), 0, stream>>>(hs, ws);
  k_score<<<dim3(256), dim3(256), 0, stream>>>(ws);
  k_out<<<dim3(1024), dim3(256), 0, stream>>>(primary, out, ws);
}

// Round 2
// 135.965 us; speedup vs baseline: 1.0935x; 1.0935x over previous
//
#include <hip/hip_runtime.h>
#include <stdint.h>

// ============================ problem dims ============================
// hidden_states [4,2048,2048] f32, rows R=8192, H=2048, BD=N=VBD=256, top-8
// out = primary + sigmoid(top1) * gelu_lowrank(softmax_top8 @ gathered vals)
// Key restructure: down-proj is linear -> precompute PV = slot_values @ Wd^T
// (256x256) and gather from PV instead of materializing aux[8192][2048].

typedef float f32x4 __attribute__((ext_vector_type(4)));
typedef unsigned short u16x8 __attribute__((ext_vector_type(8)));
typedef unsigned short u16x4 __attribute__((ext_vector_type(4)));
typedef __bf16 bf16x8 __attribute__((ext_vector_type(8)));

// ============================ ws layout (bytes) ============================
#define WS_QW    0u          // u16 [256*2048]  q_proj_w bf16
#define WS_SK    1048576u    // u16 [256*256]   slot_keys bf16
#define WS_SV    1179648u    // u16 [256*2048]  slot_values bf16
#define WS_VDW   2228224u    // u16 [256*2048]  value_down_w bf16
#define WS_VUP   3276800u    // u16 [2048*256]  value_up_w bf16
#define WS_REL   4325376u    // f32 [256]       log(reliability)
#define WS_PV    4326400u    // f32 [256*256]   slot_values @ Wd^T
#define WS_GATE  4588544u    // f32 [8192]      sigmoid(top1)
#define WS_QP    4621312u    // f32 [2][8192][256] query split-K partials
#define WS_D     21398528u   // u16 [8192*256]  gelu(down) bf16
// total ~24.4 MB

static __device__ __forceinline__ unsigned short f2bf(float f) {
  union { float f; unsigned int u; } v; v.f = f;
  unsigned int r = v.u + 0x7FFFu + ((v.u >> 16) & 1u);
  return (unsigned short)(r >> 16);
}
static __device__ __forceinline__ bf16x8 as_bf16(u16x8 v) {
  return __builtin_bit_cast(bf16x8, v);
}
static __device__ __forceinline__ float gelu_tanh(float x) {
  float u = 0.7978845608028654f * (x + 0.044715f * x * x * x);
  return 0.5f * x * (1.0f + tanhf(u));
}

// ============================ K0: convert weights ============================
__global__ void k_prep(const float* __restrict__ qw, const float* __restrict__ sk,
                       const float* __restrict__ sv, const float* __restrict__ vdw,
                       const float* __restrict__ vup, const float* __restrict__ rel,
                       unsigned char* __restrict__ ws) {
  unsigned short* o_qw  = (unsigned short*)(ws + WS_QW);
  unsigned short* o_sk  = (unsigned short*)(ws + WS_SK);
  unsigned short* o_sv  = (unsigned short*)(ws + WS_SV);
  unsigned short* o_vdw = (unsigned short*)(ws + WS_VDW);
  unsigned short* o_vup = (unsigned short*)(ws + WS_VUP);
  float* o_rel = (float*)(ws + WS_REL);
  int tid = blockIdx.x * blockDim.x + threadIdx.x;
  int stride = gridDim.x * blockDim.x;
  for (int g = tid; g < 540736; g += stride) {
    const float* src; unsigned short* dst; int i;
    if      (g < 131072) { src = qw;  dst = o_qw;  i = g; }
    else if (g < 147456) { src = sk;  dst = o_sk;  i = g - 131072; }
    else if (g < 278528) { src = sv;  dst = o_sv;  i = g - 147456; }
    else if (g < 409600) { src = vdw; dst = o_vdw; i = g - 278528; }
    else if (g < 540672) { src = vup; dst = o_vup; i = g - 409600; }
    else {
      int i4 = (g - 540672) * 4;
      #pragma unroll
      for (int j = 0; j < 4; j++) o_rel[i4 + j] = logf(fmaxf(rel[i4 + j], 1e-10f));
      continue;
    }
    f32x4 v = *(const f32x4*)(src + (size_t)i * 4);
    u16x4 o;
    #pragma unroll
    for (int j = 0; j < 4; j++) o[j] = f2bf(v[j]);
    *(u16x4*)(dst + (size_t)i * 4) = o;
  }
}

// ============================ K_PV: PV = sv @ vdw^T ============================
// 64 blocks, each a 32x32 tile over K=2048. 4 waves, one 16x16 frag each.
__global__ __launch_bounds__(256, 2) void k_pv(unsigned char* __restrict__ ws) {
  const unsigned short* sv  = (const unsigned short*)(ws + WS_SV);
  const unsigned short* vdw = (const unsigned short*)(ws + WS_VDW);
  float* PV = (float*)(ws + WS_PV);
  __shared__ __align__(16) unsigned short As[32 * 64];
  __shared__ __align__(16) unsigned short Bs[32 * 64];
  int t = threadIdx.x, lane = t & 63, w = t >> 6;
  int nt = blockIdx.x >> 3, vt = blockIdx.x & 7;
  int mf = w >> 1, nf = w & 1;
  f32x4 acc = {0.f, 0.f, 0.f, 0.f};
  int r = t >> 3, c = t & 7;
  int sw8 = (c ^ (r & 7)) * 8;
  for (int k0 = 0; k0 < 2048; k0 += 64) {
    __syncthreads();
    *(u16x8*)&As[r * 64 + sw8] = *(const u16x8*)&sv[(size_t)(nt * 32 + r) * 2048 + k0 + c * 8];
    *(u16x8*)&Bs[r * 64 + sw8] = *(const u16x8*)&vdw[(size_t)(vt * 32 + r) * 2048 + k0 + c * 8];
    __syncthreads();
    #pragma unroll
    for (int kk = 0; kk < 2; kk++) {
      int ck = kk * 4 + (lane >> 4);
      int ar = mf * 16 + (lane & 15);
      int br = nf * 16 + (lane & 15);
      bf16x8 a = as_bf16(*(const u16x8*)&As[ar * 64 + ((ck ^ (ar & 7)) * 8)]);
      bf16x8 b = as_bf16(*(const u16x8*)&Bs[br * 64 + ((ck ^ (br & 7)) * 8)]);
      acc = __builtin_amdgcn_mfma_f32_16x16x32_bf16(a, b, acc, 0, 0, 0);
    }
  }
  int row = nt * 32 + mf * 16 + (lane >> 4) * 4;
  int col = vt * 32 + nf * 16 + (lane & 15);
  #pragma unroll
  for (int j = 0; j < 4; j++) PV[(row + j) * 256 + col] = acc[j];
}

// ============================ K1: query GEMM (split-K=2) ============================
// qpart[ks][r][d] = hs[r, ks*1024 : +1024] @ qw^T.  BM=64, BN=256(all of BD).
// 256 blocks (128 row tiles x 2 k-slices), 4 waves, wave = 64x64.
__global__ __launch_bounds__(256, 2) void k_query(const float* __restrict__ hs,
                                                  unsigned char* __restrict__ ws) {
  const unsigned short* qw = (const unsigned short*)(ws + WS_QW);
  float* qp = (float*)(ws + WS_QP);
  __shared__ __align__(16) unsigned short As[64 * 64];    // 8 KB
  __shared__ __align__(16) unsigned short Bs[256 * 64];   // 32 KB
  int t = threadIdx.x, lane = t & 63, w = t >> 6;
  int rt = blockIdx.x >> 1, ks = blockIdx.x & 1;
  int row0 = rt * 64, kbase = ks * 1024;
  f32x4 acc[4][4] = {};
  int ar = t >> 2, aq = t & 3;   // A staging: row ar, 16-col chunk aq
  for (int k0 = 0; k0 < 1024; k0 += 64) {
    int kk0 = kbase + k0;
    __syncthreads();
    { // A: 64x64 fp32 -> bf16, swizzled
      const float* src = hs + (size_t)(row0 + ar) * 2048 + kk0 + aq * 16;
      f32x4 v0 = *(const f32x4*)(src);
      f32x4 v1 = *(const f32x4*)(src + 4);
      f32x4 v2 = *(const f32x4*)(src + 8);
      f32x4 v3 = *(const f32x4*)(src + 12);
      u16x8 p0, p1;
      #pragma unroll
      for (int j = 0; j < 4; j++) {
        p0[j] = f2bf(v0[j]); p0[4 + j] = f2bf(v1[j]);
        p1[j] = f2bf(v2[j]); p1[4 + j] = f2bf(v3[j]);
      }
      int c0 = aq * 2;
      *(u16x8*)&As[ar * 64 + ((c0 ^ (ar & 7)) * 8)]       = p0;
      *(u16x8*)&As[ar * 64 + (((c0 + 1) ^ (ar & 7)) * 8)] = p1;
    }
    #pragma unroll
    for (int i = 0; i < 8; i++) { // B: 256x64 bf16, swizzled
      int id = i * 256 + t, n = id >> 3, c = id & 7;
      u16x8 v = *(const u16x8*)&qw[(size_t)n * 2048 + kk0 + c * 8];
      *(u16x8*)&Bs[n * 64 + ((c ^ (n & 7)) * 8)] = v;
    }
    __syncthreads();
    #pragma unroll
    for (int kk = 0; kk < 2; kk++) {
      int ck = kk * 4 + (lane >> 4);
      bf16x8 a[4], b[4];
      #pragma unroll
      for (int mf = 0; mf < 4; mf++) {
        int arow = mf * 16 + (lane & 15);
        a[mf] = as_bf16(*(const u16x8*)&As[arow * 64 + ((ck ^ (arow & 7)) * 8)]);
      }
      #pragma unroll
      for (int nf = 0; nf < 4; nf++) {
        int brow = w * 64 + nf * 16 + (lane & 15);
        b[nf] = as_bf16(*(const u16x8*)&Bs[brow * 64 + ((ck ^ (brow & 7)) * 8)]);
      }
      #pragma unroll
      for (int mf = 0; mf < 4; mf++)
        #pragma unroll
        for (int nf = 0; nf < 4; nf++)
          acc[mf][nf] = __builtin_amdgcn_mfma_f32_16x16x32_bf16(a[mf], b[nf], acc[mf][nf], 0, 0, 0);
    }
  }
  float* outp = qp + (size_t)ks * 8192 * 256;
  #pragma unroll
  for (int mf = 0; mf < 4; mf++) {
    int row = row0 + mf * 16 + (lane >> 4) * 4;
    #pragma unroll
    for (int nf = 0; nf < 4; nf++) {
      int col = w * 64 + nf * 16 + (lane & 15);
      #pragma unroll
      for (int j = 0; j < 4; j++) outp[(size_t)(row + j) * 256 + col] = acc[mf][nf][j];
    }
  }
}

// ============================ K2: scores + top8 + softmax + PV gather ============================
#define QSTR 264   // ushort stride (528B = 33*16 -> 2-way banks, 16B aligned)
#define SSTR 260
static __device__ __forceinline__ void top8_ins(float (&bs)[8], int (&bi)[8], float s, int idx) {
  if (s > bs[7]) {
    bs[7] = s; bi[7] = idx;
    #pragma unroll
    for (int j = 7; j > 0; j--) {
      if (bs[j] > bs[j - 1]) {
        float ts = bs[j]; bs[j] = bs[j - 1]; bs[j - 1] = ts;
        int ti = bi[j]; bi[j] = bi[j - 1]; bi[j - 1] = ti;
      }
    }
  }
}
__global__ __launch_bounds__(256, 2) void k_score(unsigned char* __restrict__ ws) {
  const float* qp = (const float*)(ws + WS_QP);
  const unsigned short* sk = (const unsigned short*)(ws + WS_SK);
  const float* relm = (const float*)(ws + WS_REL);
  const float* PV = (const float*)(ws + WS_PV);
  float* gates = (float*)(ws + WS_GATE);
  unsigned short* D = (unsigned short*)(ws + WS_D);
  __shared__ __align__(16) unsigned short Qs[32 * QSTR];
  __shared__ __align__(16) float Ss[32 * SSTR];
  __shared__ float cs[32][64];
  __shared__ unsigned char ci[32][64];
  __shared__ float w8[32][8];
  __shared__ int i8[32][8];
  int t = threadIdx.x, lane = t & 63, w = t >> 6;
  int row0 = blockIdx.x * 32;
  // phase 1: query = qpart0 + qpart1 -> bf16 -> LDS
  #pragma unroll
  for (int i = 0; i < 8; i++) {
    int id = i * 256 + t, r = id >> 6, c4 = id & 63;
    const float* p0 = qp + (size_t)(row0 + r) * 256 + c4 * 4;
    f32x4 a = *(const f32x4*)p0;
    f32x4 b = *(const f32x4*)(p0 + 8192 * 256);
    u16x4 o;
    #pragma unroll
    for (int j = 0; j < 4; j++) o[j] = f2bf(a[j] + b[j]);
    *(u16x4*)&Qs[r * QSTR + c4 * 4] = o;
  }
  __syncthreads();
  // phase 2: scores[32][256] = Q @ sk^T / 16 + rel_mask
  {
    f32x4 acc[2][4] = {};
    for (int ksb = 0; ksb < 8; ksb++) {
      int ck = lane >> 4;
      bf16x8 a[2];
      #pragma unroll
      for (int mf = 0; mf < 2; mf++) {
        int arow = mf * 16 + (lane & 15);
        a[mf] = as_bf16(*(const u16x8*)&Qs[arow * QSTR + ksb * 32 + ck * 8]);
      }
      #pragma unroll
      for (int nf = 0; nf < 4; nf++) {
        int n = w * 64 + nf * 16 + (lane & 15);
        bf16x8 b = as_bf16(*(const u16x8*)&sk[(size_t)n * 256 + ksb * 32 + ck * 8]);
        #pragma unroll
        for (int mf = 0; mf < 2; mf++)
          acc[mf][nf] = __builtin_amdgcn_mfma_f32_16x16x32_bf16(a[mf], b, acc[mf][nf], 0, 0, 0);
      }
    }
    #pragma unroll
    for (int mf = 0; mf < 2; mf++)
      #pragma unroll
      for (int nf = 0; nf < 4; nf++) {
        int n = w * 64 + nf * 16 + (lane & 15);
        float rm = relm[n];
        int rr = mf * 16 + (lane >> 4) * 4;
        #pragma unroll
        for (int j = 0; j < 4; j++) Ss[(rr + j) * SSTR + n] = acc[mf][nf][j] * 0.0625f + rm;
      }
  }
  __syncthreads();
  // phase 3a: per-thread top8 over a 32-col chunk
  {
    int r = t >> 3, ch = t & 7;
    float bs[8]; int bi[8];
    #pragma unroll
    for (int j = 0; j < 8; j++) { bs[j] = -3.402823466e38f; bi[j] = 0; }
    for (int c = 0; c < 32; c++) top8_ins(bs, bi, Ss[r * SSTR + ch * 32 + c], ch * 32 + c);
    #pragma unroll
    for (int j = 0; j < 8; j++) { cs[r][ch * 8 + j] = bs[j]; ci[r][ch * 8 + j] = (unsigned char)bi[j]; }
  }
  __syncthreads();
  // phase 3b: merge 64 candidates, softmax, gate
  if ((t & 7) == 0) {
    int r = t >> 3;
    float bs[8]; int bi[8];
    #pragma unroll
    for (int j = 0; j < 8; j++) { bs[j] = -3.402823466e38f; bi[j] = 0; }
    for (int q = 0; q < 64; q++) top8_ins(bs, bi, cs[r][q], (int)ci[r][q]);
    float m = bs[0], sum = 0.f, e[8];
    #pragma unroll
    for (int j = 0; j < 8; j++) { e[j] = expf(bs[j] - m); sum += e[j]; }
    float inv = 1.f / sum;
    #pragma unroll
    for (int j = 0; j < 8; j++) { w8[r][j] = e[j] * inv; i8[r][j] = bi[j]; }
    gates[row0 + r] = 1.f / (1.f + expf(-m));
  }
  __syncthreads();
  // phase 4: D[r,v] = gelu( sum_k w_k * PV[idx_k, v] ) -> bf16
  {
    int r = t >> 3, ch = t & 7;
    float accv[32];
    #pragma unroll
    for (int j = 0; j < 32; j++) accv[j] = 0.f;
    #pragma unroll
    for (int k = 0; k < 8; k++) {
      float wk = w8[r][k];
      const float* pv = PV + (size_t)i8[r][k] * 256 + ch * 32;
      #pragma unroll
      for (int v4 = 0; v4 < 8; v4++) {
        f32x4 p = *(const f32x4*)(pv + v4 * 4);
        #pragma unroll
        for (int j = 0; j < 4; j++) accv[v4 * 4 + j] += wk * p[j];
      }
    }
    unsigned short* dd = D + (size_t)(row0 + r) * 256 + ch * 32;
    #pragma unroll
    for (int v8 = 0; v8 < 4; v8++) {
      u16x8 o;
      #pragma unroll
      for (int j = 0; j < 8; j++) o[j] = f2bf(gelu_tanh(accv[v8 * 8 + j]));
      *(u16x8*)&dd[v8 * 8] = o;
    }
  }
}

// ============================ K3: up-GEMM + epilogue ============================
// out[r,h] = primary[r,h] + gate[r] * (D[r,:] @ vup[h,:])   K=256
// 1024 blocks (64 row x 16 col tiles), XCD-chunk swizzle, 4 waves 2x2.
// Epilogue: LDS-restage acc (4 chunks of 32x128 f32, stride 132) reusing the
// As/Bs LDS via union -> fully coalesced f32x4 primary-read / out-write.
union KOutLds {
  unsigned short AB[2][128 * 64];  // As = AB[0], Bs = AB[1]  (32 KB)
  float stage[32 * 132];           // 16.5 KB, inside AB footprint
};
__global__ __launch_bounds__(256, 4) void k_out(const float* __restrict__ primary,
                                                float* __restrict__ out,
                                                unsigned char* __restrict__ ws) {
  const unsigned short* D = (const unsigned short*)(ws + WS_D);
  const unsigned short* vup = (const unsigned short*)(ws + WS_VUP);
  const float* gates = (const float*)(ws + WS_GATE);
  __shared__ __align__(16) KOutLds u;
  __shared__ float gate_s[128];
  unsigned short* As = u.AB[0];
  unsigned short* Bs = u.AB[1];
  int t = threadIdx.x, lane = t & 63, w = t >> 6;
  int bid = blockIdx.x;
  int L = (bid & 7) * 128 + (bid >> 3);   // bijective: 1024 % 8 == 0
  int rt = L >> 4, ct = L & 15;
  int wm = w >> 1, wn = w & 1;
  f32x4 acc[4][4] = {};
  if (t < 128) gate_s[t] = gates[rt * 128 + t];
  for (int k0 = 0; k0 < 256; k0 += 64) {
    __syncthreads();
    #pragma unroll
    for (int i = 0; i < 4; i++) {
      int id = i * 256 + t, r = id >> 3, c = id & 7;
      int sw8 = (c ^ (r & 7)) * 8;
      *(u16x8*)&As[r * 64 + sw8] = *(const u16x8*)&D[(size_t)(rt * 128 + r) * 256 + k0 + c * 8];
      *(u16x8*)&Bs[r * 64 + sw8] = *(const u16x8*)&vup[(size_t)(ct * 128 + r) * 256 + k0 + c * 8];
    }
    __syncthreads();
    #pragma unroll
    for (int kk = 0; kk < 2; kk++) {
      int ck = kk * 4 + (lane >> 4);
      bf16x8 a[4], b[4];
      #pragma unroll
      for (int mf = 0; mf < 4; mf++) {
        int ar = wm * 64 + mf * 16 + (lane & 15);
        a[mf] = as_bf16(*(const u16x8*)&As[ar * 64 + ((ck ^ (ar & 7)) * 8)]);
      }
      #pragma unroll
      for (int nf = 0; nf < 4; nf++) {
        int br = wn * 64 + nf * 16 + (lane & 15);
        b[nf] = as_bf16(*(const u16x8*)&Bs[br * 64 + ((ck ^ (br & 7)) * 8)]);
      }
      #pragma unroll
      for (int mf = 0; mf < 4; mf++)
        #pragma unroll
        for (int nf = 0; nf < 4; nf++)
          acc[mf][nf] = __builtin_amdgcn_mfma_f32_16x16x32_bf16(a[mf], b[nf], acc[mf][nf], 0, 0, 0);
    }
  }
  // ---- coalesced epilogue: 4 chunks of 32 rows x 128 cols ----
  #pragma unroll
  for (int c = 0; c < 4; c++) {
    __syncthreads();   // prior readers of LDS done
    if (wm == (c >> 1)) {
      #pragma unroll
      for (int mi = 0; mi < 2; mi++) {
        int mf = (c & 1) * 2 + mi;
        #pragma unroll
        for (int nf = 0; nf < 4; nf++) {
          int col = wn * 64 + nf * 16 + (lane & 15);
          #pragma unroll
          for (int j = 0; j < 4; j++) {
            int r = mi * 16 + (lane >> 4) * 4 + j;
            u.stage[r * 132 + col] = acc[mf][nf][j];
          }
        }
      }
    }
    __syncthreads();
    #pragma unroll
    for (int i = 0; i < 4; i++) {
      int idx = i * 256 + t, r = idx >> 5, c4 = idx & 31;
      int row = rt * 128 + c * 32 + r;
      size_t o = (size_t)row * 2048 + ct * 128 + c4 * 4;
      f32x4 p = *(const f32x4*)(primary + o);
      f32x4 s = *(const f32x4*)&u.stage[r * 132 + c4 * 4];
      float g = gate_s[c * 32 + r];
      f32x4 ov;
      #pragma unroll
      for (int j = 0; j < 4; j++) ov[j] = p[j] + g * s[j];
      *(f32x4*)(out + o) = ov;
    }
  }
}

// ============================ launch ============================
extern "C" void kernel_launch(void* const* d_in, const int* in_sizes, int n_in,
                              void* d_out, int out_size, void* d_ws, size_t ws_size,
                              hipStream_t stream) {
  const float* hs      = (const float*)d_in[0];
  const float* primary = (const float*)d_in[1];
  const float* qw      = (const float*)d_in[2];
  const float* sk      = (const float*)d_in[3];
  const float* sv      = (const float*)d_in[4];
  const float* rel     = (const float*)d_in[5];
  const float* vdw     = (const float*)d_in[6];
  const float* vup     = (const float*)d_in[7];
  unsigned char* ws = (unsigned char*)d_ws;
  float* out = (float*)d_out;

  k_prep<<<dim3(256), dim3(256), 0, stream>>>(qw, sk, sv, vdw, vup, rel, ws);
  k_pv<<<dim3(64), dim3(256), 0, stream>>>(ws);
  k_query<<<dim3(256), dim3(256), 0, stream>>>(hs, ws);
  k_score<<<dim3(256), dim3(256), 0, stream>>>(ws);
  k_out<<<dim3(1024), dim3(256), 0, stream>>>(primary, out, ws);
}

// Round 3
// 115.556 us; speedup vs baseline: 1.2866x; 1.1766x over previous
//
#include <hip/hip_runtime.h>
#include <stdint.h>

// ============================ problem dims ============================
// hidden_states [4,2048,2048] f32, rows R=8192, H=2048, BD=N=VBD=256, top-8
// out = primary + sigmoid(top1) * gelu_lowrank(softmax_top8 @ gathered vals)
// Key restructure: down-proj is linear -> precompute PV = slot_values @ Wd^T
// (256x256) and gather from PV instead of materializing aux[8192][2048].

typedef float f32x4 __attribute__((ext_vector_type(4)));
typedef unsigned short u16x8 __attribute__((ext_vector_type(8)));
typedef unsigned short u16x4 __attribute__((ext_vector_type(4)));
typedef __bf16 bf16x8 __attribute__((ext_vector_type(8)));

// ============================ ws layout (bytes) ============================
#define WS_QW    0u          // u16 [256*2048]  q_proj_w bf16
#define WS_SK    1048576u    // u16 [256*256]   slot_keys bf16
#define WS_SV    1179648u    // u16 [256*2048]  slot_values bf16
#define WS_VDW   2228224u    // u16 [256*2048]  value_down_w bf16
#define WS_VUP   3276800u    // u16 [2048*256]  value_up_w bf16
#define WS_REL   4325376u    // f32 [256]       log(reliability)
#define WS_PV    4326400u    // f32 [256*256]   slot_values @ Wd^T
#define WS_GATE  4588544u    // f32 [8192]      sigmoid(top1)
#define WS_QP    4621312u    // f32 [2][8192][256] query split-K partials
#define WS_D     21398528u   // u16 [8192*256]  gelu(down) bf16
// total ~24.4 MB

static __device__ __forceinline__ unsigned short f2bf(float f) {
  union { float f; unsigned int u; } v; v.f = f;
  unsigned int r = v.u + 0x7FFFu + ((v.u >> 16) & 1u);
  return (unsigned short)(r >> 16);
}
static __device__ __forceinline__ bf16x8 as_bf16(u16x8 v) {
  return __builtin_bit_cast(bf16x8, v);
}
static __device__ __forceinline__ float gelu_tanh(float x) {
  float u = 0.7978845608028654f * (x + 0.044715f * x * x * x);
  return 0.5f * x * (1.0f + tanhf(u));
}

// ============================ K0: convert weights ============================
__global__ void k_prep(const float* __restrict__ qw, const float* __restrict__ sk,
                       const float* __restrict__ sv, const float* __restrict__ vdw,
                       const float* __restrict__ vup, const float* __restrict__ rel,
                       unsigned char* __restrict__ ws) {
  unsigned short* o_qw  = (unsigned short*)(ws + WS_QW);
  unsigned short* o_sk  = (unsigned short*)(ws + WS_SK);
  unsigned short* o_sv  = (unsigned short*)(ws + WS_SV);
  unsigned short* o_vdw = (unsigned short*)(ws + WS_VDW);
  unsigned short* o_vup = (unsigned short*)(ws + WS_VUP);
  float* o_rel = (float*)(ws + WS_REL);
  int tid = blockIdx.x * blockDim.x + threadIdx.x;
  int stride = gridDim.x * blockDim.x;
  for (int g = tid; g < 540736; g += stride) {
    const float* src; unsigned short* dst; int i;
    if      (g < 131072) { src = qw;  dst = o_qw;  i = g; }
    else if (g < 147456) { src = sk;  dst = o_sk;  i = g - 131072; }
    else if (g < 278528) { src = sv;  dst = o_sv;  i = g - 147456; }
    else if (g < 409600) { src = vdw; dst = o_vdw; i = g - 278528; }
    else if (g < 540672) { src = vup; dst = o_vup; i = g - 409600; }
    else {
      int i4 = (g - 540672) * 4;
      #pragma unroll
      for (int j = 0; j < 4; j++) o_rel[i4 + j] = logf(fmaxf(rel[i4 + j], 1e-10f));
      continue;
    }
    f32x4 v = *(const f32x4*)(src + (size_t)i * 4);
    u16x4 o;
    #pragma unroll
    for (int j = 0; j < 4; j++) o[j] = f2bf(v[j]);
    *(u16x4*)(dst + (size_t)i * 4) = o;
  }
}

// ============================ K_PV: PV = sv @ vdw^T ============================
// 64 blocks, each a 32x32 tile over K=2048. 4 waves, one 16x16 frag each.
__global__ __launch_bounds__(256, 2) void k_pv(unsigned char* __restrict__ ws) {
  const unsigned short* sv  = (const unsigned short*)(ws + WS_SV);
  const unsigned short* vdw = (const unsigned short*)(ws + WS_VDW);
  float* PV = (float*)(ws + WS_PV);
  __shared__ __align__(16) unsigned short As[32 * 64];
  __shared__ __align__(16) unsigned short Bs[32 * 64];
  int t = threadIdx.x, lane = t & 63, w = t >> 6;
  int nt = blockIdx.x >> 3, vt = blockIdx.x & 7;
  int mf = w >> 1, nf = w & 1;
  f32x4 acc = {0.f, 0.f, 0.f, 0.f};
  int r = t >> 3, c = t & 7;
  int sw8 = (c ^ (r & 7)) * 8;
  for (int k0 = 0; k0 < 2048; k0 += 64) {
    __syncthreads();
    *(u16x8*)&As[r * 64 + sw8] = *(const u16x8*)&sv[(size_t)(nt * 32 + r) * 2048 + k0 + c * 8];
    *(u16x8*)&Bs[r * 64 + sw8] = *(const u16x8*)&vdw[(size_t)(vt * 32 + r) * 2048 + k0 + c * 8];
    __syncthreads();
    #pragma unroll
    for (int kk = 0; kk < 2; kk++) {
      int ck = kk * 4 + (lane >> 4);
      int ar = mf * 16 + (lane & 15);
      int br = nf * 16 + (lane & 15);
      bf16x8 a = as_bf16(*(const u16x8*)&As[ar * 64 + ((ck ^ (ar & 7)) * 8)]);
      bf16x8 b = as_bf16(*(const u16x8*)&Bs[br * 64 + ((ck ^ (br & 7)) * 8)]);
      acc = __builtin_amdgcn_mfma_f32_16x16x32_bf16(a, b, acc, 0, 0, 0);
    }
  }
  int row = nt * 32 + mf * 16 + (lane >> 4) * 4;
  int col = vt * 32 + nf * 16 + (lane & 15);
  #pragma unroll
  for (int j = 0; j < 4; j++) PV[(row + j) * 256 + col] = acc[j];
}

// ============================ K1: query GEMM (split-K=2) ============================
// qpart[ks][r][d] = hs[r, ks*1024 : +1024] @ qw^T.  BM=64, BN=256(all of BD).
// 256 blocks (128 row tiles x 2 k-slices), 4 waves, wave = 64x64.
__global__ __launch_bounds__(256, 2) void k_query(const float* __restrict__ hs,
                                                  unsigned char* __restrict__ ws) {
  const unsigned short* qw = (const unsigned short*)(ws + WS_QW);
  float* qp = (float*)(ws + WS_QP);
  __shared__ __align__(16) unsigned short As[64 * 64];    // 8 KB
  __shared__ __align__(16) unsigned short Bs[256 * 64];   // 32 KB
  int t = threadIdx.x, lane = t & 63, w = t >> 6;
  int rt = blockIdx.x >> 1, ks = blockIdx.x & 1;
  int row0 = rt * 64, kbase = ks * 1024;
  f32x4 acc[4][4] = {};
  int ar = t >> 2, aq = t & 3;   // A staging: row ar, 16-col chunk aq
  for (int k0 = 0; k0 < 1024; k0 += 64) {
    int kk0 = kbase + k0;
    __syncthreads();
    { // A: 64x64 fp32 -> bf16, swizzled
      const float* src = hs + (size_t)(row0 + ar) * 2048 + kk0 + aq * 16;
      f32x4 v0 = *(const f32x4*)(src);
      f32x4 v1 = *(const f32x4*)(src + 4);
      f32x4 v2 = *(const f32x4*)(src + 8);
      f32x4 v3 = *(const f32x4*)(src + 12);
      u16x8 p0, p1;
      #pragma unroll
      for (int j = 0; j < 4; j++) {
        p0[j] = f2bf(v0[j]); p0[4 + j] = f2bf(v1[j]);
        p1[j] = f2bf(v2[j]); p1[4 + j] = f2bf(v3[j]);
      }
      int c0 = aq * 2;
      *(u16x8*)&As[ar * 64 + ((c0 ^ (ar & 7)) * 8)]       = p0;
      *(u16x8*)&As[ar * 64 + (((c0 + 1) ^ (ar & 7)) * 8)] = p1;
    }
    #pragma unroll
    for (int i = 0; i < 8; i++) { // B: 256x64 bf16, swizzled
      int id = i * 256 + t, n = id >> 3, c = id & 7;
      u16x8 v = *(const u16x8*)&qw[(size_t)n * 2048 + kk0 + c * 8];
      *(u16x8*)&Bs[n * 64 + ((c ^ (n & 7)) * 8)] = v;
    }
    __syncthreads();
    #pragma unroll
    for (int kk = 0; kk < 2; kk++) {
      int ck = kk * 4 + (lane >> 4);
      bf16x8 a[4], b[4];
      #pragma unroll
      for (int mf = 0; mf < 4; mf++) {
        int arow = mf * 16 + (lane & 15);
        a[mf] = as_bf16(*(const u16x8*)&As[arow * 64 + ((ck ^ (arow & 7)) * 8)]);
      }
      #pragma unroll
      for (int nf = 0; nf < 4; nf++) {
        int brow = w * 64 + nf * 16 + (lane & 15);
        b[nf] = as_bf16(*(const u16x8*)&Bs[brow * 64 + ((ck ^ (brow & 7)) * 8)]);
      }
      #pragma unroll
      for (int mf = 0; mf < 4; mf++)
        #pragma unroll
        for (int nf = 0; nf < 4; nf++)
          acc[mf][nf] = __builtin_amdgcn_mfma_f32_16x16x32_bf16(a[mf], b[nf], acc[mf][nf], 0, 0, 0);
    }
  }
  float* outp = qp + (size_t)ks * 8192 * 256;
  #pragma unroll
  for (int mf = 0; mf < 4; mf++) {
    int row = row0 + mf * 16 + (lane >> 4) * 4;
    #pragma unroll
    for (int nf = 0; nf < 4; nf++) {
      int col = w * 64 + nf * 16 + (lane & 15);
      #pragma unroll
      for (int j = 0; j < 4; j++) outp[(size_t)(row + j) * 256 + col] = acc[mf][nf][j];
    }
  }
}

// ============================ K2: scores + wave-parallel top8 + PV gather ============================
// 512 blocks x 16 rows. Phase 1: Q=qp0+qp1 -> bf16 LDS. Phase 2: MFMA scores
// -> Ss (stride 260 f32, per-row reads contiguous). Phase 3: one WAVE per row:
// pack (ordered-score|255-idx) u32, 8x {max4 + 6-step shfl_xor butterfly max,
// owner masks winner}; all lanes decode winners redundantly (no LDS, no
// divergence), softmax + gate, coalesced f32x4 PV gather, gelu -> D bf16.
#define QSTR 264   // ushort stride
#define SSTR 260   // f32 stride: 1040B row -> 16B aligned, contiguous reads
__global__ __launch_bounds__(256, 4) void k_score(unsigned char* __restrict__ ws) {
  const float* qp = (const float*)(ws + WS_QP);
  const unsigned short* sk = (const unsigned short*)(ws + WS_SK);
  const float* relm = (const float*)(ws + WS_REL);
  const float* PV = (const float*)(ws + WS_PV);
  float* gates = (float*)(ws + WS_GATE);
  unsigned short* D = (unsigned short*)(ws + WS_D);
  __shared__ __align__(16) unsigned short Qs[16 * QSTR];
  __shared__ __align__(16) float Ss[16 * SSTR];
  int t = threadIdx.x, lane = t & 63, w = t >> 6;
  int row0 = blockIdx.x * 16;
  // phase 1: query = qpart0 + qpart1 -> bf16 -> LDS (16 rows x 256 cols)
  #pragma unroll
  for (int i = 0; i < 4; i++) {
    int id = i * 256 + t, r = id >> 6, c4 = id & 63;
    const float* p0 = qp + (size_t)(row0 + r) * 256 + c4 * 4;
    f32x4 a = *(const f32x4*)p0;
    f32x4 b = *(const f32x4*)(p0 + 8192 * 256);
    u16x4 o;
    #pragma unroll
    for (int j = 0; j < 4; j++) o[j] = f2bf(a[j] + b[j]);
    *(u16x4*)&Qs[r * QSTR + c4 * 4] = o;
  }
  __syncthreads();
  // phase 2: scores[16][256] = Q @ sk^T / 16 + rel_mask
  {
    f32x4 acc[4] = {};
    for (int ksb = 0; ksb < 8; ksb++) {
      int ck = lane >> 4;
      bf16x8 a = as_bf16(*(const u16x8*)&Qs[(lane & 15) * QSTR + ksb * 32 + ck * 8]);
      #pragma unroll
      for (int nf = 0; nf < 4; nf++) {
        int n = w * 64 + nf * 16 + (lane & 15);
        bf16x8 b = as_bf16(*(const u16x8*)&sk[(size_t)n * 256 + ksb * 32 + ck * 8]);
        acc[nf] = __builtin_amdgcn_mfma_f32_16x16x32_bf16(a, b, acc[nf], 0, 0, 0);
      }
    }
    #pragma unroll
    for (int nf = 0; nf < 4; nf++) {
      int n = w * 64 + nf * 16 + (lane & 15);
      float rm = relm[n];
      int rr = (lane >> 4) * 4;
      #pragma unroll
      for (int j = 0; j < 4; j++) Ss[(rr + j) * SSTR + n] = acc[nf][j] * 0.0625f + rm;
    }
  }
  __syncthreads();
  // phase 3: wave w handles rows w*4 .. w*4+3
  for (int rr = 0; rr < 4; rr++) {
    int row = w * 4 + rr;
    f32x4 sv4 = *(const f32x4*)&Ss[row * SSTR + lane * 4];
    unsigned int key[4];
    #pragma unroll
    for (int j = 0; j < 4; j++) {
      unsigned int u = __builtin_bit_cast(unsigned int, sv4[j]);
      unsigned int os = (u & 0x80000000u) ? ~u : (u | 0x80000000u);
      key[j] = (os & 0xFFFFFF00u) | (unsigned int)(255 - (lane * 4 + j));
    }
    unsigned int win[8];
    #pragma unroll
    for (int e = 0; e < 8; e++) {
      unsigned int m01 = key[0] > key[1] ? key[0] : key[1];
      unsigned int m23 = key[2] > key[3] ? key[2] : key[3];
      unsigned int m = m01 > m23 ? m01 : m23;
      #pragma unroll
      for (int d = 1; d < 64; d <<= 1) {
        unsigned int o = (unsigned int)__shfl_xor((int)m, d, 64);
        m = o > m ? o : m;
      }
      win[e] = m;
      #pragma unroll
      for (int j = 0; j < 4; j++) if (key[j] == m) key[j] = 0u;
    }
    // decode (all lanes redundantly)
    float s8[8]; int i8[8];
    #pragma unroll
    for (int e = 0; e < 8; e++) {
      i8[e] = 255 - (int)(win[e] & 0xFFu);
      unsigned int os = win[e] & 0xFFFFFF00u;
      unsigned int u = (os & 0x80000000u) ? (os ^ 0x80000000u) : ~os;
      s8[e] = __builtin_bit_cast(float, u);
    }
    float m0 = s8[0], sum = 0.f, we[8];
    #pragma unroll
    for (int e = 0; e < 8; e++) { we[e] = expf(s8[e] - m0); sum += we[e]; }
    float inv = 1.f / sum;
    // PV gather: lane l owns cols 4l..4l+3 (f32x4, contiguous 1KB per slot)
    f32x4 accv = {0.f, 0.f, 0.f, 0.f};
    #pragma unroll
    for (int e = 0; e < 8; e++) {
      float wk = we[e] * inv;
      f32x4 p = *(const f32x4*)(PV + (size_t)i8[e] * 256 + lane * 4);
      #pragma unroll
      for (int j = 0; j < 4; j++) accv[j] += wk * p[j];
    }
    u16x4 o;
    #pragma unroll
    for (int j = 0; j < 4; j++) o[j] = f2bf(gelu_tanh(accv[j]));
    *(u16x4*)&D[(size_t)(row0 + row) * 256 + lane * 4] = o;
    if (lane == 0) gates[row0 + row] = 1.f / (1.f + expf(-m0));
  }
}

// ============================ K3: up-GEMM + epilogue ============================
// out[r,h] = primary[r,h] + gate[r] * (D[r,:] @ vup[h,:])   K=256
// 1024 blocks (64 row x 16 col tiles), XCD-chunk swizzle, 4 waves 2x2.
// Epilogue: LDS-restage acc (4 chunks of 32x128 f32, stride 132) reusing the
// As/Bs LDS via union -> fully coalesced f32x4 primary-read / out-write.
union KOutLds {
  unsigned short AB[2][128 * 64];  // As = AB[0], Bs = AB[1]  (32 KB)
  float stage[32 * 132];           // 16.5 KB, inside AB footprint
};
__global__ __launch_bounds__(256, 4) void k_out(const float* __restrict__ primary,
                                                float* __restrict__ out,
                                                unsigned char* __restrict__ ws) {
  const unsigned short* D = (const unsigned short*)(ws + WS_D);
  const unsigned short* vup = (const unsigned short*)(ws + WS_VUP);
  const float* gates = (const float*)(ws + WS_GATE);
  __shared__ __align__(16) KOutLds u;
  __shared__ float gate_s[128];
  unsigned short* As = u.AB[0];
  unsigned short* Bs = u.AB[1];
  int t = threadIdx.x, lane = t & 63, w = t >> 6;
  int bid = blockIdx.x;
  int L = (bid & 7) * 128 + (bid >> 3);   // bijective: 1024 % 8 == 0
  int rt = L >> 4, ct = L & 15;
  int wm = w >> 1, wn = w & 1;
  f32x4 acc[4][4] = {};
  if (t < 128) gate_s[t] = gates[rt * 128 + t];
  for (int k0 = 0; k0 < 256; k0 += 64) {
    __syncthreads();
    #pragma unroll
    for (int i = 0; i < 4; i++) {
      int id = i * 256 + t, r = id >> 3, c = id & 7;
      int sw8 = (c ^ (r & 7)) * 8;
      *(u16x8*)&As[r * 64 + sw8] = *(const u16x8*)&D[(size_t)(rt * 128 + r) * 256 + k0 + c * 8];
      *(u16x8*)&Bs[r * 64 + sw8] = *(const u16x8*)&vup[(size_t)(ct * 128 + r) * 256 + k0 + c * 8];
    }
    __syncthreads();
    #pragma unroll
    for (int kk = 0; kk < 2; kk++) {
      int ck = kk * 4 + (lane >> 4);
      bf16x8 a[4], b[4];
      #pragma unroll
      for (int mf = 0; mf < 4; mf++) {
        int ar = wm * 64 + mf * 16 + (lane & 15);
        a[mf] = as_bf16(*(const u16x8*)&As[ar * 64 + ((ck ^ (ar & 7)) * 8)]);
      }
      #pragma unroll
      for (int nf = 0; nf < 4; nf++) {
        int br = wn * 64 + nf * 16 + (lane & 15);
        b[nf] = as_bf16(*(const u16x8*)&Bs[br * 64 + ((ck ^ (br & 7)) * 8)]);
      }
      #pragma unroll
      for (int mf = 0; mf < 4; mf++)
        #pragma unroll
        for (int nf = 0; nf < 4; nf++)
          acc[mf][nf] = __builtin_amdgcn_mfma_f32_16x16x32_bf16(a[mf], b[nf], acc[mf][nf], 0, 0, 0);
    }
  }
  // ---- coalesced epilogue: 4 chunks of 32 rows x 128 cols ----
  #pragma unroll
  for (int c = 0; c < 4; c++) {
    __syncthreads();   // prior readers of LDS done
    if (wm == (c >> 1)) {
      #pragma unroll
      for (int mi = 0; mi < 2; mi++) {
        int mf = (c & 1) * 2 + mi;
        #pragma unroll
        for (int nf = 0; nf < 4; nf++) {
          int col = wn * 64 + nf * 16 + (lane & 15);
          #pragma unroll
          for (int j = 0; j < 4; j++) {
            int r = mi * 16 + (lane >> 4) * 4 + j;
            u.stage[r * 132 + col] = acc[mf][nf][j];
          }
        }
      }
    }
    __syncthreads();
    #pragma unroll
    for (int i = 0; i < 4; i++) {
      int idx = i * 256 + t, r = idx >> 5, c4 = idx & 31;
      int row = rt * 128 + c * 32 + r;
      size_t o = (size_t)row * 2048 + ct * 128 + c4 * 4;
      f32x4 p = *(const f32x4*)(primary + o);
      f32x4 s = *(const f32x4*)&u.stage[r * 132 + c4 * 4];
      float g = gate_s[c * 32 + r];
      f32x4 ov;
      #pragma unroll
      for (int j = 0; j < 4; j++) ov[j] = p[j] + g * s[j];
      *(f32x4*)(out + o) = ov;
    }
  }
}

// ============================ launch ============================
extern "C" void kernel_launch(void* const* d_in, const int* in_sizes, int n_in,
                              void* d_out, int out_size, void* d_ws, size_t ws_size,
                              hipStream_t stream) {
  const float* hs      = (const float*)d_in[0];
  const float* primary = (const float*)d_in[1];
  const float* qw      = (const float*)d_in[2];
  const float* sk      = (const float*)d_in[3];
  const float* sv      = (const float*)d_in[4];
  const float* rel     = (const float*)d_in[5];
  const float* vdw     = (const float*)d_in[6];
  const float* vup     = (const float*)d_in[7];
  unsigned char* ws = (unsigned char*)d_ws;
  float* out = (float*)d_out;

  k_prep<<<dim3(256), dim3(256), 0, stream>>>(qw, sk, sv, vdw, vup, rel, ws);
  k_pv<<<dim3(64), dim3(256), 0, stream>>>(ws);
  k_query<<<dim3(256), dim3(256), 0, stream>>>(hs, ws);
  k_score<<<dim3(512), dim3(256), 0, stream>>>(ws);
  k_out<<<dim3(1024), dim3(256), 0, stream>>>(primary, out, ws);
}

// Round 4
// 96.238 us; speedup vs baseline: 1.5448x; 1.2007x over previous
//
#include <hip/hip_runtime.h>
#include <stdint.h>

// ============================ problem dims ============================
// hidden_states [4,2048,2048] f32, rows R=8192, H=2048, BD=N=VBD=256, top-8
// out = primary + sigmoid(top1) * gelu_lowrank(softmax_top8 @ gathered vals)
// Key restructure: down-proj is linear -> precompute PV = slot_values @ Wd^T
// (256x256) and gather from PV instead of materializing aux[8192][2048].

typedef float f32x4 __attribute__((ext_vector_type(4)));
typedef unsigned short u16x8 __attribute__((ext_vector_type(8)));
typedef unsigned short u16x4 __attribute__((ext_vector_type(4)));
typedef __bf16 bf16x8 __attribute__((ext_vector_type(8)));

// ============================ ws layout (bytes) ============================
#define WS_QW    0u          // u16 [256*2048]  q_proj_w bf16
#define WS_SK    1048576u    // u16 [256*256]   slot_keys bf16
#define WS_SV    1179648u    // u16 [256*2048]  slot_values bf16
#define WS_VDW   2228224u    // u16 [256*2048]  value_down_w bf16
#define WS_VUP   3276800u    // u16 [2048*256]  value_up_w bf16
#define WS_REL   4325376u    // f32 [256]       log(reliability)
#define WS_PV    4326400u    // f32 [256*256]   slot_values @ Wd^T
#define WS_GATE  4588544u    // f32 [8192]      sigmoid(top1)
#define WS_QP    4621312u    // f32 [2][8192][256] query split-K partials
#define WS_D     21398528u   // u16 [8192*256]  gelu(down) bf16
// total ~24.4 MB

static __device__ __forceinline__ unsigned short f2bf(float f) {
  union { float f; unsigned int u; } v; v.f = f;
  unsigned int r = v.u + 0x7FFFu + ((v.u >> 16) & 1u);
  return (unsigned short)(r >> 16);
}
static __device__ __forceinline__ bf16x8 as_bf16(u16x8 v) {
  return __builtin_bit_cast(bf16x8, v);
}
static __device__ __forceinline__ float gelu_tanh(float x) {
  float u = 0.7978845608028654f * (x + 0.044715f * x * x * x);
  return 0.5f * x * (1.0f + tanhf(u));
}

// ============================ K0: convert weights ============================
__global__ void k_prep(const float* __restrict__ qw, const float* __restrict__ sk,
                       const float* __restrict__ sv, const float* __restrict__ vdw,
                       const float* __restrict__ vup, const float* __restrict__ rel,
                       unsigned char* __restrict__ ws) {
  unsigned short* o_qw  = (unsigned short*)(ws + WS_QW);
  unsigned short* o_sk  = (unsigned short*)(ws + WS_SK);
  unsigned short* o_sv  = (unsigned short*)(ws + WS_SV);
  unsigned short* o_vdw = (unsigned short*)(ws + WS_VDW);
  unsigned short* o_vup = (unsigned short*)(ws + WS_VUP);
  float* o_rel = (float*)(ws + WS_REL);
  int tid = blockIdx.x * blockDim.x + threadIdx.x;
  int stride = gridDim.x * blockDim.x;
  for (int g = tid; g < 540736; g += stride) {
    const float* src; unsigned short* dst; int i;
    if      (g < 131072) { src = qw;  dst = o_qw;  i = g; }
    else if (g < 147456) { src = sk;  dst = o_sk;  i = g - 131072; }
    else if (g < 278528) { src = sv;  dst = o_sv;  i = g - 147456; }
    else if (g < 409600) { src = vdw; dst = o_vdw; i = g - 278528; }
    else if (g < 540672) { src = vup; dst = o_vup; i = g - 409600; }
    else {
      int i4 = (g - 540672) * 4;
      #pragma unroll
      for (int j = 0; j < 4; j++) o_rel[i4 + j] = logf(fmaxf(rel[i4 + j], 1e-10f));
      continue;
    }
    f32x4 v = *(const f32x4*)(src + (size_t)i * 4);
    u16x4 o;
    #pragma unroll
    for (int j = 0; j < 4; j++) o[j] = f2bf(v[j]);
    *(u16x4*)(dst + (size_t)i * 4) = o;
  }
}

// ============================ K_PV: PV = sv @ vdw^T ============================
// 64 blocks, each a 32x32 tile over K=2048. 4 waves, one 16x16 frag each.
__global__ __launch_bounds__(256, 2) void k_pv(unsigned char* __restrict__ ws) {
  const unsigned short* sv  = (const unsigned short*)(ws + WS_SV);
  const unsigned short* vdw = (const unsigned short*)(ws + WS_VDW);
  float* PV = (float*)(ws + WS_PV);
  __shared__ __align__(16) unsigned short As[32 * 64];
  __shared__ __align__(16) unsigned short Bs[32 * 64];
  int t = threadIdx.x, lane = t & 63, w = t >> 6;
  int nt = blockIdx.x >> 3, vt = blockIdx.x & 7;
  int mf = w >> 1, nf = w & 1;
  f32x4 acc = {0.f, 0.f, 0.f, 0.f};
  int r = t >> 3, c = t & 7;
  int sw8 = (c ^ (r & 7)) * 8;
  for (int k0 = 0; k0 < 2048; k0 += 64) {
    __syncthreads();
    *(u16x8*)&As[r * 64 + sw8] = *(const u16x8*)&sv[(size_t)(nt * 32 + r) * 2048 + k0 + c * 8];
    *(u16x8*)&Bs[r * 64 + sw8] = *(const u16x8*)&vdw[(size_t)(vt * 32 + r) * 2048 + k0 + c * 8];
    __syncthreads();
    #pragma unroll
    for (int kk = 0; kk < 2; kk++) {
      int ck = kk * 4 + (lane >> 4);
      int ar = mf * 16 + (lane & 15);
      int br = nf * 16 + (lane & 15);
      bf16x8 a = as_bf16(*(const u16x8*)&As[ar * 64 + ((ck ^ (ar & 7)) * 8)]);
      bf16x8 b = as_bf16(*(const u16x8*)&Bs[br * 64 + ((ck ^ (br & 7)) * 8)]);
      acc = __builtin_amdgcn_mfma_f32_16x16x32_bf16(a, b, acc, 0, 0, 0);
    }
  }
  int row = nt * 32 + mf * 16 + (lane >> 4) * 4;
  int col = vt * 32 + nf * 16 + (lane & 15);
  #pragma unroll
  for (int j = 0; j < 4; j++) PV[(row + j) * 256 + col] = acc[j];
}

// ============================ K1: query GEMM (split-K=2, pipelined) ============================
// qpart[ks][r][d] = hs[r, ks*1024 : +1024] @ qw^T.  BM=32, BN=256(all of BD).
// 512 blocks (256 row tiles x 2 k-slices) -> 2-4 blocks/CU.  4 waves, each
// owns 32x64 (2 mfrag x 4 nfrag).  Register-prefetch pipeline: issue tile
// t+1's global loads right after staging tile t, before the MFMA phase, so
// HBM latency hides under compute + the next barrier.
__global__ __launch_bounds__(256, 4) void k_query(const float* __restrict__ hs,
                                                  unsigned char* __restrict__ ws) {
  const unsigned short* qw = (const unsigned short*)(ws + WS_QW);
  float* qp = (float*)(ws + WS_QP);
  __shared__ __align__(16) unsigned short As[32 * 64];    // 4 KB
  __shared__ __align__(16) unsigned short Bs[256 * 64];   // 32 KB
  int t = threadIdx.x, lane = t & 63, w = t >> 6;
  int rt = blockIdx.x >> 1, ks = blockIdx.x & 1;
  int row0 = rt * 32, kbase = ks * 1024;
  f32x4 acc[2][4] = {};
  int sr = t >> 3, sc = t & 7;   // staging coords: 32 rows x 8 chunks of 8
  const float* aptr = hs + (size_t)(row0 + sr) * 2048 + kbase + sc * 8;
  const unsigned short* bptr = qw + (size_t)sr * 2048 + kbase + sc * 8;
  f32x4 pa0, pa1;
  u16x8 pb0, pb1, pb2, pb3, pb4, pb5, pb6, pb7;
  // prologue: tile 0 -> regs
  pa0 = *(const f32x4*)(aptr);
  pa1 = *(const f32x4*)(aptr + 4);
  pb0 = *(const u16x8*)(bptr + (size_t)0 * 32 * 2048);
  pb1 = *(const u16x8*)(bptr + (size_t)1 * 32 * 2048);
  pb2 = *(const u16x8*)(bptr + (size_t)2 * 32 * 2048);
  pb3 = *(const u16x8*)(bptr + (size_t)3 * 32 * 2048);
  pb4 = *(const u16x8*)(bptr + (size_t)4 * 32 * 2048);
  pb5 = *(const u16x8*)(bptr + (size_t)5 * 32 * 2048);
  pb6 = *(const u16x8*)(bptr + (size_t)6 * 32 * 2048);
  pb7 = *(const u16x8*)(bptr + (size_t)7 * 32 * 2048);
  for (int kt = 0; kt < 16; kt++) {
    __syncthreads();   // previous tile's LDS readers done
    {  // stage regs -> LDS (A: fp32->bf16)
      u16x8 o;
      #pragma unroll
      for (int j = 0; j < 4; j++) { o[j] = f2bf(pa0[j]); o[4 + j] = f2bf(pa1[j]); }
      *(u16x8*)&As[sr * 64 + ((sc ^ (sr & 7)) * 8)] = o;
      u16x8 pb[8] = {pb0, pb1, pb2, pb3, pb4, pb5, pb6, pb7};
      #pragma unroll
      for (int i = 0; i < 8; i++) {
        int n = i * 32 + sr;
        *(u16x8*)&Bs[n * 64 + ((sc ^ (n & 7)) * 8)] = pb[i];
      }
    }
    __syncthreads();
    if (kt < 15) {  // prefetch tile kt+1 into regs (overlaps MFMA below)
      int off = (kt + 1) * 64;
      pa0 = *(const f32x4*)(aptr + off);
      pa1 = *(const f32x4*)(aptr + off + 4);
      pb0 = *(const u16x8*)(bptr + (size_t)0 * 32 * 2048 + off);
      pb1 = *(const u16x8*)(bptr + (size_t)1 * 32 * 2048 + off);
      pb2 = *(const u16x8*)(bptr + (size_t)2 * 32 * 2048 + off);
      pb3 = *(const u16x8*)(bptr + (size_t)3 * 32 * 2048 + off);
      pb4 = *(const u16x8*)(bptr + (size_t)4 * 32 * 2048 + off);
      pb5 = *(const u16x8*)(bptr + (size_t)5 * 32 * 2048 + off);
      pb6 = *(const u16x8*)(bptr + (size_t)6 * 32 * 2048 + off);
      pb7 = *(const u16x8*)(bptr + (size_t)7 * 32 * 2048 + off);
    }
    #pragma unroll
    for (int kk = 0; kk < 2; kk++) {
      int ck = kk * 4 + (lane >> 4);
      bf16x8 a[2], b[4];
      #pragma unroll
      for (int mf = 0; mf < 2; mf++) {
        int arow = mf * 16 + (lane & 15);
        a[mf] = as_bf16(*(const u16x8*)&As[arow * 64 + ((ck ^ (arow & 7)) * 8)]);
      }
      #pragma unroll
      for (int nf = 0; nf < 4; nf++) {
        int brow = w * 64 + nf * 16 + (lane & 15);
        b[nf] = as_bf16(*(const u16x8*)&Bs[brow * 64 + ((ck ^ (brow & 7)) * 8)]);
      }
      #pragma unroll
      for (int mf = 0; mf < 2; mf++)
        #pragma unroll
        for (int nf = 0; nf < 4; nf++)
          acc[mf][nf] = __builtin_amdgcn_mfma_f32_16x16x32_bf16(a[mf], b[nf], acc[mf][nf], 0, 0, 0);
    }
  }
  float* outp = qp + (size_t)ks * 8192 * 256;
  #pragma unroll
  for (int mf = 0; mf < 2; mf++) {
    int row = row0 + mf * 16 + (lane >> 4) * 4;
    #pragma unroll
    for (int nf = 0; nf < 4; nf++) {
      int col = w * 64 + nf * 16 + (lane & 15);
      #pragma unroll
      for (int j = 0; j < 4; j++) outp[(size_t)(row + j) * 256 + col] = acc[mf][nf][j];
    }
  }
}

// ============================ K2: scores + wave-parallel top8 + PV gather ============================
// 512 blocks x 16 rows. Phase 1: Q=qp0+qp1 -> bf16 LDS. Phase 2: MFMA scores
// -> Ss (stride 260 f32, per-row reads contiguous). Phase 3: one WAVE per row:
// pack (ordered-score|255-idx) u32, 8x {max4 + 6-step shfl_xor butterfly max,
// owner masks winner}; all lanes decode winners redundantly (no LDS, no
// divergence), softmax + gate, coalesced f32x4 PV gather, gelu -> D bf16.
#define QSTR 264   // ushort stride
#define SSTR 260   // f32 stride: 1040B row -> 16B aligned, contiguous reads
__global__ __launch_bounds__(256, 4) void k_score(unsigned char* __restrict__ ws) {
  const float* qp = (const float*)(ws + WS_QP);
  const unsigned short* sk = (const unsigned short*)(ws + WS_SK);
  const float* relm = (const float*)(ws + WS_REL);
  const float* PV = (const float*)(ws + WS_PV);
  float* gates = (float*)(ws + WS_GATE);
  unsigned short* D = (unsigned short*)(ws + WS_D);
  __shared__ __align__(16) unsigned short Qs[16 * QSTR];
  __shared__ __align__(16) float Ss[16 * SSTR];
  int t = threadIdx.x, lane = t & 63, w = t >> 6;
  int row0 = blockIdx.x * 16;
  // phase 1: query = qpart0 + qpart1 -> bf16 -> LDS (16 rows x 256 cols)
  #pragma unroll
  for (int i = 0; i < 4; i++) {
    int id = i * 256 + t, r = id >> 6, c4 = id & 63;
    const float* p0 = qp + (size_t)(row0 + r) * 256 + c4 * 4;
    f32x4 a = *(const f32x4*)p0;
    f32x4 b = *(const f32x4*)(p0 + 8192 * 256);
    u16x4 o;
    #pragma unroll
    for (int j = 0; j < 4; j++) o[j] = f2bf(a[j] + b[j]);
    *(u16x4*)&Qs[r * QSTR + c4 * 4] = o;
  }
  __syncthreads();
  // phase 2: scores[16][256] = Q @ sk^T / 16 + rel_mask
  {
    f32x4 acc[4] = {};
    for (int ksb = 0; ksb < 8; ksb++) {
      int ck = lane >> 4;
      bf16x8 a = as_bf16(*(const u16x8*)&Qs[(lane & 15) * QSTR + ksb * 32 + ck * 8]);
      #pragma unroll
      for (int nf = 0; nf < 4; nf++) {
        int n = w * 64 + nf * 16 + (lane & 15);
        bf16x8 b = as_bf16(*(const u16x8*)&sk[(size_t)n * 256 + ksb * 32 + ck * 8]);
        acc[nf] = __builtin_amdgcn_mfma_f32_16x16x32_bf16(a, b, acc[nf], 0, 0, 0);
      }
    }
    #pragma unroll
    for (int nf = 0; nf < 4; nf++) {
      int n = w * 64 + nf * 16 + (lane & 15);
      float rm = relm[n];
      int rr = (lane >> 4) * 4;
      #pragma unroll
      for (int j = 0; j < 4; j++) Ss[(rr + j) * SSTR + n] = acc[nf][j] * 0.0625f + rm;
    }
  }
  __syncthreads();
  // phase 3: wave w handles rows w*4 .. w*4+3
  for (int rr = 0; rr < 4; rr++) {
    int row = w * 4 + rr;
    f32x4 sv4 = *(const f32x4*)&Ss[row * SSTR + lane * 4];
    unsigned int key[4];
    #pragma unroll
    for (int j = 0; j < 4; j++) {
      unsigned int u = __builtin_bit_cast(unsigned int, sv4[j]);
      unsigned int os = (u & 0x80000000u) ? ~u : (u | 0x80000000u);
      key[j] = (os & 0xFFFFFF00u) | (unsigned int)(255 - (lane * 4 + j));
    }
    unsigned int win[8];
    #pragma unroll
    for (int e = 0; e < 8; e++) {
      unsigned int m01 = key[0] > key[1] ? key[0] : key[1];
      unsigned int m23 = key[2] > key[3] ? key[2] : key[3];
      unsigned int m = m01 > m23 ? m01 : m23;
      #pragma unroll
      for (int d = 1; d < 64; d <<= 1) {
        unsigned int o = (unsigned int)__shfl_xor((int)m, d, 64);
        m = o > m ? o : m;
      }
      win[e] = m;
      #pragma unroll
      for (int j = 0; j < 4; j++) if (key[j] == m) key[j] = 0u;
    }
    // decode (all lanes redundantly)
    float s8[8]; int i8[8];
    #pragma unroll
    for (int e = 0; e < 8; e++) {
      i8[e] = 255 - (int)(win[e] & 0xFFu);
      unsigned int os = win[e] & 0xFFFFFF00u;
      unsigned int u = (os & 0x80000000u) ? (os ^ 0x80000000u) : ~os;
      s8[e] = __builtin_bit_cast(float, u);
    }
    float m0 = s8[0], sum = 0.f, we[8];
    #pragma unroll
    for (int e = 0; e < 8; e++) { we[e] = expf(s8[e] - m0); sum += we[e]; }
    float inv = 1.f / sum;
    // PV gather: lane l owns cols 4l..4l+3 (f32x4, contiguous 1KB per slot)
    f32x4 accv = {0.f, 0.f, 0.f, 0.f};
    #pragma unroll
    for (int e = 0; e < 8; e++) {
      float wk = we[e] * inv;
      f32x4 p = *(const f32x4*)(PV + (size_t)i8[e] * 256 + lane * 4);
      #pragma unroll
      for (int j = 0; j < 4; j++) accv[j] += wk * p[j];
    }
    u16x4 o;
    #pragma unroll
    for (int j = 0; j < 4; j++) o[j] = f2bf(gelu_tanh(accv[j]));
    *(u16x4*)&D[(size_t)(row0 + row) * 256 + lane * 4] = o;
    if (lane == 0) gates[row0 + row] = 1.f / (1.f + expf(-m0));
  }
}

// ============================ K3: up-GEMM + epilogue ============================
// out[r,h] = primary[r,h] + gate[r] * (D[r,:] @ vup[h,:])   K=256
// 1024 blocks (64 row x 16 col tiles), XCD-chunk swizzle, 4 waves 2x2.
// Epilogue: LDS-restage acc (4 chunks of 32x128 f32, stride 132) reusing the
// As/Bs LDS via union -> fully coalesced f32x4 primary-read / out-write.
union KOutLds {
  unsigned short AB[2][128 * 64];  // As = AB[0], Bs = AB[1]  (32 KB)
  float stage[32 * 132];           // 16.5 KB, inside AB footprint
};
__global__ __launch_bounds__(256, 4) void k_out(const float* __restrict__ primary,
                                                float* __restrict__ out,
                                                unsigned char* __restrict__ ws) {
  const unsigned short* D = (const unsigned short*)(ws + WS_D);
  const unsigned short* vup = (const unsigned short*)(ws + WS_VUP);
  const float* gates = (const float*)(ws + WS_GATE);
  __shared__ __align__(16) KOutLds u;
  __shared__ float gate_s[128];
  unsigned short* As = u.AB[0];
  unsigned short* Bs = u.AB[1];
  int t = threadIdx.x, lane = t & 63, w = t >> 6;
  int bid = blockIdx.x;
  int L = (bid & 7) * 128 + (bid >> 3);   // bijective: 1024 % 8 == 0
  int rt = L >> 4, ct = L & 15;
  int wm = w >> 1, wn = w & 1;
  f32x4 acc[4][4] = {};
  if (t < 128) gate_s[t] = gates[rt * 128 + t];
  for (int k0 = 0; k0 < 256; k0 += 64) {
    __syncthreads();
    #pragma unroll
    for (int i = 0; i < 4; i++) {
      int id = i * 256 + t, r = id >> 3, c = id & 7;
      int sw8 = (c ^ (r & 7)) * 8;
      *(u16x8*)&As[r * 64 + sw8] = *(const u16x8*)&D[(size_t)(rt * 128 + r) * 256 + k0 + c * 8];
      *(u16x8*)&Bs[r * 64 + sw8] = *(const u16x8*)&vup[(size_t)(ct * 128 + r) * 256 + k0 + c * 8];
    }
    __syncthreads();
    #pragma unroll
    for (int kk = 0; kk < 2; kk++) {
      int ck = kk * 4 + (lane >> 4);
      bf16x8 a[4], b[4];
      #pragma unroll
      for (int mf = 0; mf < 4; mf++) {
        int ar = wm * 64 + mf * 16 + (lane & 15);
        a[mf] = as_bf16(*(const u16x8*)&As[ar * 64 + ((ck ^ (ar & 7)) * 8)]);
      }
      #pragma unroll
      for (int nf = 0; nf < 4; nf++) {
        int br = wn * 64 + nf * 16 + (lane & 15);
        b[nf] = as_bf16(*(const u16x8*)&Bs[br * 64 + ((ck ^ (br & 7)) * 8)]);
      }
      #pragma unroll
      for (int mf = 0; mf < 4; mf++)
        #pragma unroll
        for (int nf = 0; nf < 4; nf++)
          acc[mf][nf] = __builtin_amdgcn_mfma_f32_16x16x32_bf16(a[mf], b[nf], acc[mf][nf], 0, 0, 0);
    }
  }
  // ---- coalesced epilogue: 4 chunks of 32 rows x 128 cols ----
  #pragma unroll
  for (int c = 0; c < 4; c++) {
    __syncthreads();   // prior readers of LDS done
    if (wm == (c >> 1)) {
      #pragma unroll
      for (int mi = 0; mi < 2; mi++) {
        int mf = (c & 1) * 2 + mi;
        #pragma unroll
        for (int nf = 0; nf < 4; nf++) {
          int col = wn * 64 + nf * 16 + (lane & 15);
          #pragma unroll
          for (int j = 0; j < 4; j++) {
            int r = mi * 16 + (lane >> 4) * 4 + j;
            u.stage[r * 132 + col] = acc[mf][nf][j];
          }
        }
      }
    }
    __syncthreads();
    #pragma unroll
    for (int i = 0; i < 4; i++) {
      int idx = i * 256 + t, r = idx >> 5, c4 = idx & 31;
      int row = rt * 128 + c * 32 + r;
      size_t o = (size_t)row * 2048 + ct * 128 + c4 * 4;
      f32x4 p = *(const f32x4*)(primary + o);
      f32x4 s = *(const f32x4*)&u.stage[r * 132 + c4 * 4];
      float g = gate_s[c * 32 + r];
      f32x4 ov;
      #pragma unroll
      for (int j = 0; j < 4; j++) ov[j] = p[j] + g * s[j];
      *(f32x4*)(out + o) = ov;
    }
  }
}

// ============================ launch ============================
extern "C" void kernel_launch(void* const* d_in, const int* in_sizes, int n_in,
                              void* d_out, int out_size, void* d_ws, size_t ws_size,
                              hipStream_t stream) {
  const float* hs      = (const float*)d_in[0];
  const float* primary = (const float*)d_in[1];
  const float* qw      = (const float*)d_in[2];
  const float* sk      = (const float*)d_in[3];
  const float* sv      = (const float*)d_in[4];
  const float* rel     = (const float*)d_in[5];
  const float* vdw     = (const float*)d_in[6];
  const float* vup     = (const float*)d_in[7];
  unsigned char* ws = (unsigned char*)d_ws;
  float* out = (float*)d_out;

  k_prep<<<dim3(256), dim3(256), 0, stream>>>(qw, sk, sv, vdw, vup, rel, ws);
  k_pv<<<dim3(64), dim3(256), 0, stream>>>(ws);
  k_query<<<dim3(512), dim3(256), 0, stream>>>(hs, ws);
  k_score<<<dim3(512), dim3(256), 0, stream>>>(ws);
  k_out<<<dim3(1024), dim3(256), 0, stream>>>(primary, out, ws);
}